// Round 9
// baseline (264.224 us; speedup 1.0000x reference)
//
#include <hip/hip_runtime.h>
#include <hip/hip_bf16.h>
#include <float.h>

// Problem constants (from setup_inputs): B=16, N=21504, C=80, G=64, K=9
#define BB 16
#define NN 21504
#define CC 80
#define GG 64
#define KK 9
#define NSEG 8
#define SEG4 (NN / 2 / NSEG)   // float4s per segment: 10752/8 = 1344
#define T4   (SEG4 / 64)       // 21 float4 iterations per lane

// ---------------- focal helpers ----------------
__device__ __forceinline__ float focal_t0(float x) {
    float ax = fabsf(x);
    float em = __expf(-ax);
    float sp = __logf(1.0f + em);
    float spx = fmaxf(x, 0.0f) + sp;     // softplus(x)
    float r = 1.0f / (1.0f + em);
    float p = (x >= 0.0f) ? r : em * r;  // sigmoid(x)
    return 0.75f * spx * p * p;
}

__device__ __forceinline__ float focal_corr(float x) {
    float ax = fabsf(x);
    float em = __expf(-ax);
    float sp = __logf(1.0f + em);
    float spx = fmaxf(x, 0.0f) + sp;
    float spn = fmaxf(-x, 0.0f) + sp;
    float r = 1.0f / (1.0f + em);
    float p = (x >= 0.0f) ? r : em * r;
    float q = 1.0f - p;
    float f1 = 0.25f * spn * q * q;
    float f0 = 0.75f * spx * p * p;
    return f1 - f0;
}

// one shared distance function so both scans produce bit-identical values
__device__ __forceinline__ float d2f(float cx, float cy, float x, float y) {
    float dx = cx - x, dy = cy - y;
    return dx * dx + dy * dy;
}

// Kernel A1: one wave per (pair, segment); NSEG=8 segments per pair.
// 2048 blocks x 4 waves = 8192 waves -> 8 waves/SIMD for chain interleaving.
// Threshold top-9 within the segment (registers+shuffles only), writes the
// segment's 9 smallest (d2, n) to workspace.
__global__ __launch_bounds__(256) void topk_seg_kernel(
    const float* __restrict__ locations,   // (N,2)
    const float* __restrict__ gt_boxes,    // (B,G,4)
    float* __restrict__ cand_d,            // (1024*NSEG*KK)
    int*   __restrict__ cand_n)
{
    int wv   = threadIdx.x >> 6;
    int lane = threadIdx.x & 63;
    int w    = blockIdx.x * 4 + wv;        // global wave id 0..8191
    int pair = w >> 3;                     // 0..1023
    int seg  = w & (NSEG - 1);             // 0..7
    int b = pair >> 6;
    int g = pair & (GG - 1);

    const float4 gt = ((const float4*)gt_boxes)[b * GG + g];
    float cx = gt.x, cy = gt.y;
    const float4* loc4 = (const float4*)locations;
    int base4 = seg * SEG4 + lane;

    // Scan 1: per-lane min over 42 points (21 float4s, 2 pts each)
    float m0 = FLT_MAX, m1 = FLT_MAX;
#pragma unroll 7
    for (int t = 0; t < T4; ++t) {
        float4 A = loc4[base4 + t * 64];
        m0 = fminf(m0, d2f(cx, cy, A.x, A.y));
        m1 = fminf(m1, d2f(cx, cy, A.z, A.w));
    }
    float md = fminf(m0, m1);

    // T = 9th-smallest lane-min (ties only enlarge T -> superset, safe)
    float v = md;
    float T = FLT_MAX;
    for (int r = 0; r < KK; ++r) {
        float m = v;
        for (int s = 1; s < 64; s <<= 1) m = fminf(m, __shfl_xor(m, s));
        T = m;
        if (v == m) v = FLT_MAX;
    }

    // Scan 2: collect candidates d2 <= T, up to 6 per lane in named scalars
    float sd0 = FLT_MAX, sd1 = FLT_MAX, sd2 = FLT_MAX,
          sd3 = FLT_MAX, sd4 = FLT_MAX, sd5 = FLT_MAX;
    int   sn0 = 0x7fffffff, sn1 = 0x7fffffff, sn2 = 0x7fffffff,
          sn3 = 0x7fffffff, sn4 = 0x7fffffff, sn5 = 0x7fffffff;
    int cnt = 0;
#define PUSH(dv, nv)                                             \
    do {                                                         \
        if (cnt == 0)      { sd0 = dv; sn0 = nv; }               \
        else if (cnt == 1) { sd1 = dv; sn1 = nv; }               \
        else if (cnt == 2) { sd2 = dv; sn2 = nv; }               \
        else if (cnt == 3) { sd3 = dv; sn3 = nv; }               \
        else if (cnt == 4) { sd4 = dv; sn4 = nv; }               \
        else if (cnt == 5) { sd5 = dv; sn5 = nv; }               \
        ++cnt;                                                   \
    } while (0)

#pragma unroll 3
    for (int t = 0; t < T4; ++t) {
        int i4 = base4 + t * 64;
        float4 A = loc4[i4];
        float da = d2f(cx, cy, A.x, A.y);
        float db = d2f(cx, cy, A.z, A.w);
        if (da <= T) PUSH(da, 2 * i4);
        if (db <= T) PUSH(db, 2 * i4 + 1);
    }
#undef PUSH

    int ovf = (cnt > 6) ? 1 : 0;
    for (int s = 1; s < 64; s <<= 1) ovf = max(ovf, __shfl_xor(ovf, s));

    int obase = (pair * NSEG + seg) * KK;
    if (ovf == 0) {
        // 9 butterfly lex-min extraction rounds over the slots
        for (int r = 0; r < KK; ++r) {
            float bv = sd0; int bn = sn0;
            bool c;
            c = sd1 < bv; bv = c ? sd1 : bv; bn = c ? sn1 : bn;
            c = sd2 < bv; bv = c ? sd2 : bv; bn = c ? sn2 : bn;
            c = sd3 < bv; bv = c ? sd3 : bv; bn = c ? sn3 : bn;
            c = sd4 < bv; bv = c ? sd4 : bv; bn = c ? sn4 : bn;
            c = sd5 < bv; bv = c ? sd5 : bv; bn = c ? sn5 : bn;
            for (int s = 1; s < 64; s <<= 1) {
                float ov = __shfl_xor(bv, s);
                int   on = __shfl_xor(bn, s);
                bool cc = (ov < bv) || (ov == bv && on < bn);
                bv = cc ? ov : bv;
                bn = cc ? on : bn;
            }
            if (sn0 == bn) sd0 = FLT_MAX;
            if (sn1 == bn) sd1 = FLT_MAX;
            if (sn2 == bn) sd2 = FLT_MAX;
            if (sn3 == bn) sd3 = FLT_MAX;
            if (sn4 == bn) sd4 = FLT_MAX;
            if (sn5 == bn) sd5 = FLT_MAX;
            if (lane == 0) { cand_d[obase + r] = bv; cand_n[obase + r] = bn; }
        }
    } else {
        // rare exact fallback: 9 lex-min rescans of this segment
        float lastD = -1.0f; int lastN = -1;
        for (int r = 0; r < KK; ++r) {
            float bv = FLT_MAX; int bn = 0x7fffffff;
            for (int t = 0; t < T4; ++t) {
                int i4 = base4 + t * 64;
                float4 A = loc4[i4];
                float da = d2f(cx, cy, A.x, A.y);
                float db = d2f(cx, cy, A.z, A.w);
                int na = 2 * i4, nb = 2 * i4 + 1;
                bool ga = (da > lastD) || (da == lastD && na > lastN);
                bool ca = ga && ((da < bv) || (da == bv && na < bn));
                bv = ca ? da : bv; bn = ca ? na : bn;
                bool gb = (db > lastD) || (db == lastD && nb > lastN);
                bool cb = gb && ((db < bv) || (db == bv && nb < bn));
                bv = cb ? db : bv; bn = cb ? nb : bn;
            }
            for (int s = 1; s < 64; s <<= 1) {
                float ov = __shfl_xor(bv, s);
                int   on = __shfl_xor(bn, s);
                bool cc = (ov < bv) || (ov == bv && on < bn);
                bv = cc ? ov : bv;
                bn = cc ? on : bn;
            }
            lastD = bv; lastN = bn;
            if (lane == 0) { cand_d[obase + r] = bv; cand_n[obase + r] = bn; }
        }
    }
}

// Kernel A2: one wave per pair merges 72 candidates (2 slots/lane),
// extracts the global top-9 and does the bbox L1 + GIoU epilogue.
__global__ __launch_bounds__(256) void topk_merge_kernel(
    const float* __restrict__ pred_boxes,  // (B,N,4)
    const float* __restrict__ gt_boxes,    // (B,G,4)
    const float* __restrict__ cand_d,
    const int*   __restrict__ cand_n,
    double* __restrict__ acc,
    int* __restrict__ sel)
{
    int wv   = threadIdx.x >> 6;
    int lane = threadIdx.x & 63;
    int pair = blockIdx.x * 4 + wv;        // 0..1023
    int b = pair >> 6;
    int g = pair & (GG - 1);

    const float4 gt = ((const float4*)gt_boxes)[b * GG + g];

    int cb = pair * NSEG * KK;             // 72 candidates
    float vd0 = cand_d[cb + lane];         // lanes 0..63 all valid (<72)
    int   vn0 = cand_n[cb + lane];
    float vd1 = FLT_MAX; int vn1 = 0x7fffffff;
    if (lane + 64 < NSEG * KK) {           // lanes 0..7
        vd1 = cand_d[cb + lane + 64];
        vn1 = cand_n[cb + lane + 64];
    }

    int myn = 0;
    for (int r = 0; r < KK; ++r) {
        bool cl = (vd1 < vd0) || (vd1 == vd0 && vn1 < vn0);
        float bv = cl ? vd1 : vd0;
        int   bn = cl ? vn1 : vn0;
        for (int s = 1; s < 64; s <<= 1) {
            float ov = __shfl_xor(bv, s);
            int   on = __shfl_xor(bn, s);
            bool cc = (ov < bv) || (ov == bv && on < bn);
            bv = cc ? ov : bv;
            bn = cc ? on : bn;
        }
        if (vn0 == bn) vd0 = FLT_MAX;      // n unique across all slots
        if (vn1 == bn) vd1 = FLT_MAX;
        if (lane == r) myn = bn;
        if (lane == 0) sel[pair * KK + r] = bn;
    }
    myn = myn < 0 ? 0 : (myn >= NN ? NN - 1 : myn);  // fault guard

    float l1 = 0.0f, gio = 0.0f;
    if (lane < KK) {
        float4 p = ((const float4*)pred_boxes)[b * NN + myn];
        l1 = fabsf(p.x - gt.x) + fabsf(p.y - gt.y) + fabsf(p.z - gt.z) + fabsf(p.w - gt.w);

        float ax1 = p.x - 0.5f * p.z, ay1 = p.y - 0.5f * p.w;
        float ax2 = p.x + 0.5f * p.z, ay2 = p.y + 0.5f * p.w;
        float bx1 = gt.x - 0.5f * gt.z, by1 = gt.y - 0.5f * gt.w;
        float bx2 = gt.x + 0.5f * gt.z, by2 = gt.y + 0.5f * gt.w;

        float area_a = (ax2 - ax1) * (ay2 - ay1);
        float area_b = (bx2 - bx1) * (by2 - by1);
        float ix1 = fmaxf(ax1, bx1), iy1 = fmaxf(ay1, by1);
        float ix2 = fminf(ax2, bx2), iy2 = fminf(ay2, by2);
        float iw = fmaxf(ix2 - ix1, 0.0f), ih = fmaxf(iy2 - iy1, 0.0f);
        float inter = iw * ih;
        float uni = area_a + area_b - inter;
        float iou = inter / uni;
        float ccx1 = fminf(ax1, bx1), ccy1 = fminf(ay1, by1);
        float ccx2 = fmaxf(ax2, bx2), ccy2 = fmaxf(ay2, by2);
        float cw = fmaxf(ccx2 - ccx1, 0.0f), ch = fmaxf(ccy2 - ccy1, 0.0f);
        float ac = cw * ch;
        float giou = iou - (ac - uni) / ac;
        gio = 1.0f - giou;
    }
    for (int o = 32; o > 0; o >>= 1) {
        l1 += __shfl_down(l1, o);
        gio += __shfl_down(gio, o);
    }
    if (lane == 0) {
        atomicAdd(&acc[1], (double)l1);
        atomicAdd(&acc[2], (double)gio);
    }
}

// Kernel B: main focal sum over all B*N*C logits (t=0 formula everywhere)
__global__ __launch_bounds__(256) void focal_main_kernel(
    const float* __restrict__ logits, double* __restrict__ acc, int nvec4)
{
    const float4* v = (const float4*)logits;
    float s0 = 0.f, s1 = 0.f, s2 = 0.f, s3 = 0.f;
    int stride = gridDim.x * blockDim.x;
    for (int i = blockIdx.x * blockDim.x + threadIdx.x; i < nvec4; i += stride) {
        float4 x = v[i];
        s0 += focal_t0(x.x);
        s1 += focal_t0(x.y);
        s2 += focal_t0(x.z);
        s3 += focal_t0(x.w);
    }
    double d = (double)((s0 + s1) + (s2 + s3));
#pragma unroll
    for (int o = 32; o > 0; o >>= 1) d += __shfl_down(d, o);
    __shared__ double wsum[4];
    if ((threadIdx.x & 63) == 0) wsum[threadIdx.x >> 6] = d;
    __syncthreads();
    if (threadIdx.x == 0) {
        atomicAdd(&acc[0], wsum[0] + wsum[1] + wsum[2] + wsum[3]);
    }
}

// Kernel C (v3): 4 blocks per image. Dedup via batched, explicitly-bitwise
// scan: 8 independent LDS reads per group (pipelined, no short-circuit
// branches, no loop-carried lgkmcnt(0) chain).
#define EPB 144   // elements per block (576 / 4)
__global__ __launch_bounds__(256) void correction_kernel(
    const float* __restrict__ logits, const int* __restrict__ sel,
    const int* __restrict__ gt_labels, double* __restrict__ acc)
{
    int bq = blockIdx.x;           // 0..63
    int b  = bq >> 2;              // image
    int q  = bq & 3;               // quarter

    __shared__ int keys[GG * KK];
    for (int e = threadIdx.x; e < GG * KK; e += blockDim.x) {
        int g = e / KK;
        int n = sel[(b * GG + g) * KK + (e - g * KK)];
        keys[e] = n * CC + gt_labels[b * GG + g];
    }
    __syncthreads();

    bool active = (threadIdx.x < EPB);
    int e = q * EPB + (active ? threadIdx.x : 0);   // bounded index
    int k = keys[e];
    k = active ? k : -1;                            // -1 never matches

    // branch-free duplicate test, 8 pipelined LDS reads per group
    int dup = 0;
    for (int e2 = 0; e2 < GG * KK; e2 += 8) {
        int k0 = keys[e2 + 0];
        int k1 = keys[e2 + 1];
        int k2 = keys[e2 + 2];
        int k3 = keys[e2 + 3];
        int k4 = keys[e2 + 4];
        int k5 = keys[e2 + 5];
        int k6 = keys[e2 + 6];
        int k7 = keys[e2 + 7];
        int h = 0;
        h |= (int)(k0 == k) & (int)(e2 + 0 < e);
        h |= (int)(k1 == k) & (int)(e2 + 1 < e);
        h |= (int)(k2 == k) & (int)(e2 + 2 < e);
        h |= (int)(k3 == k) & (int)(e2 + 3 < e);
        h |= (int)(k4 == k) & (int)(e2 + 4 < e);
        h |= (int)(k5 == k) & (int)(e2 + 5 < e);
        h |= (int)(k6 == k) & (int)(e2 + 6 < e);
        h |= (int)(k7 == k) & (int)(e2 + 7 < e);
        dup |= h;
    }

    float corr = 0.0f;
    if (active && dup == 0) {
        corr = focal_corr(logits[(long long)b * NN * CC + k]);
    }

    double d = (double)corr;
#pragma unroll
    for (int o = 32; o > 0; o >>= 1) d += __shfl_down(d, o);
    __shared__ double wsum[4];
    if ((threadIdx.x & 63) == 0) wsum[threadIdx.x >> 6] = d;
    __syncthreads();
    if (threadIdx.x == 0) {
        atomicAdd(&acc[0], wsum[0] + wsum[1] + wsum[2] + wsum[3]);
    }
}

// Kernel D: finalize means
__global__ void finalize_kernel(const double* __restrict__ acc, float* __restrict__ out)
{
    if (threadIdx.x == 0 && blockIdx.x == 0) {
        out[0] = (float)(acc[0] / (double)((long long)BB * NN * CC));
        out[1] = (float)(acc[1] / (double)(BB * GG * KK * 4));
        out[2] = (float)(acc[2] / (double)(BB * GG * KK));
    }
}

extern "C" void kernel_launch(void* const* d_in, const int* in_sizes, int n_in,
                              void* d_out, int out_size, void* d_ws, size_t ws_size,
                              hipStream_t stream) {
    const float* pred_logits = (const float*)d_in[0];  // (B,N,C)
    const float* pred_boxes  = (const float*)d_in[1];  // (B,N,4)
    const float* locations   = (const float*)d_in[2];  // (N,2)
    const float* gt_boxes    = (const float*)d_in[3];  // (B,G,4)
    const int*   gt_labels   = (const int*)d_in[4];    // (B,G)
    float* out = (float*)d_out;

    // workspace layout
    double* acc   = (double*)d_ws;                               // 3 doubles
    int*    sel   = (int*)((char*)d_ws + 64);                    // 1024*9 ints = 36864 B
    float*  candd = (float*)((char*)d_ws + 64 + 36864);          // 1024*8*9 floats = 294912 B
    int*    candn = (int*)((char*)d_ws + 64 + 36864 + 294912);   // 294912 B

    hipMemsetAsync(d_ws, 0, 64, stream);

    // A1: per-segment top-9 (2048 blocks x 4 waves = 8192 wave-segments)
    topk_seg_kernel<<<BB * GG * NSEG / 4, 256, 0, stream>>>(locations, gt_boxes, candd, candn);

    // A2: merge 72 candidates/pair + bbox epilogue (256 blocks x 4 waves)
    topk_merge_kernel<<<BB * GG / 4, 256, 0, stream>>>(pred_boxes, gt_boxes, candd, candn, acc, sel);

    // B: focal main sum
    int nvec4 = (BB * NN * CC) / 4;
    focal_main_kernel<<<2048, 256, 0, stream>>>(pred_logits, acc, nvec4);

    // C: corrections (4 blocks per image)
    correction_kernel<<<BB * 4, 256, 0, stream>>>(pred_logits, sel, gt_labels, acc);

    // D: finalize
    finalize_kernel<<<1, 64, 0, stream>>>(acc, out);
}

// Round 10
// 252.719 us; speedup vs baseline: 1.0455x; 1.0455x over previous
//
#include <hip/hip_runtime.h>
#include <hip/hip_bf16.h>
#include <float.h>

// Problem constants (from setup_inputs): B=16, N=21504, C=80, G=64, K=9
#define BB 16
#define NN 21504
#define CC 80
#define GG 64
#define KK 9
#define NSEG 4
#define SEG4 (NN / 2 / NSEG)   // float4s per segment: 10752/4 = 2688
#define T4   (SEG4 / 64)       // 42 float4 iterations per lane

// ---------------- focal helpers ----------------
__device__ __forceinline__ float focal_t0(float x) {
    float ax = fabsf(x);
    float em = __expf(-ax);
    float sp = __logf(1.0f + em);
    float spx = fmaxf(x, 0.0f) + sp;     // softplus(x)
    float r = 1.0f / (1.0f + em);
    float p = (x >= 0.0f) ? r : em * r;  // sigmoid(x)
    return 0.75f * spx * p * p;
}

__device__ __forceinline__ float focal_corr(float x) {
    float ax = fabsf(x);
    float em = __expf(-ax);
    float sp = __logf(1.0f + em);
    float spx = fmaxf(x, 0.0f) + sp;
    float spn = fmaxf(-x, 0.0f) + sp;
    float r = 1.0f / (1.0f + em);
    float p = (x >= 0.0f) ? r : em * r;
    float q = 1.0f - p;
    float f1 = 0.25f * spn * q * q;
    float f0 = 0.75f * spx * p * p;
    return f1 - f0;
}

// one shared distance function so both scans produce bit-identical values
__device__ __forceinline__ float d2f(float cx, float cy, float x, float y) {
    float dx = cx - x, dy = cy - y;
    return dx * dx + dy * dy;
}

// Kernel A1: one wave per (pair, segment); block = pair, wave = segment.
// Manual 7-deep load batching: 7 float4 loads issued into named scalars
// before ANY use, so 7 loads are in flight regardless of unroller behavior.
// Block 0 also zeroes acc + ticket (replaces the hipMemsetAsync dispatch;
// safe because no A1 block reads acc, and stream order covers A2/B/C).
__global__ __launch_bounds__(256) void topk_seg_kernel(
    const float* __restrict__ locations,   // (N,2)
    const float* __restrict__ gt_boxes,    // (B,G,4)
    float* __restrict__ cand_d,            // (1024*NSEG*KK)
    int*   __restrict__ cand_n,
    unsigned long long* __restrict__ hdr)  // 64B header: acc[3] + ticket
{
    if (blockIdx.x == 0 && threadIdx.x < 8) hdr[threadIdx.x] = 0ull;

    int seg  = threadIdx.x >> 6;           // 0..3
    int lane = threadIdx.x & 63;
    int pair = blockIdx.x;                 // 0..1023
    int b = pair >> 6;
    int g = pair & (GG - 1);

    const float4 gt = ((const float4*)gt_boxes)[b * GG + g];
    float cx = gt.x, cy = gt.y;
    const float4* loc4 = (const float4*)locations;
    int base4 = seg * SEG4 + lane;

    // Scan 1: per-lane min over 84 points; 6 groups of 7 batched loads
    float m0 = FLT_MAX, m1 = FLT_MAX, m2 = FLT_MAX, m3 = FLT_MAX;
    for (int t = 0; t < T4; t += 7) {
        float4 L0 = loc4[base4 + (t + 0) * 64];
        float4 L1 = loc4[base4 + (t + 1) * 64];
        float4 L2 = loc4[base4 + (t + 2) * 64];
        float4 L3 = loc4[base4 + (t + 3) * 64];
        float4 L4 = loc4[base4 + (t + 4) * 64];
        float4 L5 = loc4[base4 + (t + 5) * 64];
        float4 L6 = loc4[base4 + (t + 6) * 64];
        m0 = fminf(m0, fminf(d2f(cx, cy, L0.x, L0.y), d2f(cx, cy, L0.z, L0.w)));
        m1 = fminf(m1, fminf(d2f(cx, cy, L1.x, L1.y), d2f(cx, cy, L1.z, L1.w)));
        m2 = fminf(m2, fminf(d2f(cx, cy, L2.x, L2.y), d2f(cx, cy, L2.z, L2.w)));
        m3 = fminf(m3, fminf(d2f(cx, cy, L3.x, L3.y), d2f(cx, cy, L3.z, L3.w)));
        m0 = fminf(m0, fminf(d2f(cx, cy, L4.x, L4.y), d2f(cx, cy, L4.z, L4.w)));
        m1 = fminf(m1, fminf(d2f(cx, cy, L5.x, L5.y), d2f(cx, cy, L5.z, L5.w)));
        m2 = fminf(m2, fminf(d2f(cx, cy, L6.x, L6.y), d2f(cx, cy, L6.z, L6.w)));
    }
    float md = fminf(fminf(m0, m1), fminf(m2, m3));

    // T = 9th-smallest lane-min (ties only enlarge T -> superset, safe)
    float v = md;
    float T = FLT_MAX;
    for (int r = 0; r < KK; ++r) {
        float m = v;
        for (int s = 1; s < 64; s <<= 1) m = fminf(m, __shfl_xor(m, s));
        T = m;
        if (v == m) v = FLT_MAX;
    }

    // Scan 2: collect candidates d2 <= T, up to 6 per lane in named scalars;
    // same 7-deep load batching.
    float sd0 = FLT_MAX, sd1 = FLT_MAX, sd2 = FLT_MAX,
          sd3 = FLT_MAX, sd4 = FLT_MAX, sd5 = FLT_MAX;
    int   sn0 = 0x7fffffff, sn1 = 0x7fffffff, sn2 = 0x7fffffff,
          sn3 = 0x7fffffff, sn4 = 0x7fffffff, sn5 = 0x7fffffff;
    int cnt = 0;
#define PUSH(dv, nv)                                             \
    do {                                                         \
        if (cnt == 0)      { sd0 = dv; sn0 = nv; }               \
        else if (cnt == 1) { sd1 = dv; sn1 = nv; }               \
        else if (cnt == 2) { sd2 = dv; sn2 = nv; }               \
        else if (cnt == 3) { sd3 = dv; sn3 = nv; }               \
        else if (cnt == 4) { sd4 = dv; sn4 = nv; }               \
        else if (cnt == 5) { sd5 = dv; sn5 = nv; }               \
        ++cnt;                                                   \
    } while (0)
#define TEST(Lv, tt)                                             \
    do {                                                         \
        int i4 = base4 + (tt) * 64;                              \
        float da = d2f(cx, cy, Lv.x, Lv.y);                      \
        float db = d2f(cx, cy, Lv.z, Lv.w);                      \
        if (da <= T) PUSH(da, 2 * i4);                           \
        if (db <= T) PUSH(db, 2 * i4 + 1);                       \
    } while (0)

    for (int t = 0; t < T4; t += 7) {
        float4 L0 = loc4[base4 + (t + 0) * 64];
        float4 L1 = loc4[base4 + (t + 1) * 64];
        float4 L2 = loc4[base4 + (t + 2) * 64];
        float4 L3 = loc4[base4 + (t + 3) * 64];
        float4 L4 = loc4[base4 + (t + 4) * 64];
        float4 L5 = loc4[base4 + (t + 5) * 64];
        float4 L6 = loc4[base4 + (t + 6) * 64];
        TEST(L0, t + 0);
        TEST(L1, t + 1);
        TEST(L2, t + 2);
        TEST(L3, t + 3);
        TEST(L4, t + 4);
        TEST(L5, t + 5);
        TEST(L6, t + 6);
    }
#undef TEST
#undef PUSH

    int ovf = (cnt > 6) ? 1 : 0;
    for (int s = 1; s < 64; s <<= 1) ovf = max(ovf, __shfl_xor(ovf, s));

    int obase = (pair * NSEG + seg) * KK;
    if (ovf == 0) {
        // 9 butterfly lex-min extraction rounds over the slots
        for (int r = 0; r < KK; ++r) {
            float bv = sd0; int bn = sn0;
            bool c;
            c = sd1 < bv; bv = c ? sd1 : bv; bn = c ? sn1 : bn;
            c = sd2 < bv; bv = c ? sd2 : bv; bn = c ? sn2 : bn;
            c = sd3 < bv; bv = c ? sd3 : bv; bn = c ? sn3 : bn;
            c = sd4 < bv; bv = c ? sd4 : bv; bn = c ? sn4 : bn;
            c = sd5 < bv; bv = c ? sd5 : bv; bn = c ? sn5 : bn;
            for (int s = 1; s < 64; s <<= 1) {
                float ov = __shfl_xor(bv, s);
                int   on = __shfl_xor(bn, s);
                bool cc = (ov < bv) || (ov == bv && on < bn);
                bv = cc ? ov : bv;
                bn = cc ? on : bn;
            }
            if (sn0 == bn) sd0 = FLT_MAX;
            if (sn1 == bn) sd1 = FLT_MAX;
            if (sn2 == bn) sd2 = FLT_MAX;
            if (sn3 == bn) sd3 = FLT_MAX;
            if (sn4 == bn) sd4 = FLT_MAX;
            if (sn5 == bn) sd5 = FLT_MAX;
            if (lane == 0) { cand_d[obase + r] = bv; cand_n[obase + r] = bn; }
        }
    } else {
        // rare exact fallback: 9 lex-min rescans of this segment
        float lastD = -1.0f; int lastN = -1;
        for (int r = 0; r < KK; ++r) {
            float bv = FLT_MAX; int bn = 0x7fffffff;
            for (int t = 0; t < T4; ++t) {
                int i4 = base4 + t * 64;
                float4 A = loc4[i4];
                float da = d2f(cx, cy, A.x, A.y);
                float db = d2f(cx, cy, A.z, A.w);
                int na = 2 * i4, nb = 2 * i4 + 1;
                bool ga = (da > lastD) || (da == lastD && na > lastN);
                bool ca = ga && ((da < bv) || (da == bv && na < bn));
                bv = ca ? da : bv; bn = ca ? na : bn;
                bool gb = (db > lastD) || (db == lastD && nb > lastN);
                bool cb = gb && ((db < bv) || (db == bv && nb < bn));
                bv = cb ? db : bv; bn = cb ? nb : bn;
            }
            for (int s = 1; s < 64; s <<= 1) {
                float ov = __shfl_xor(bv, s);
                int   on = __shfl_xor(bn, s);
                bool cc = (ov < bv) || (ov == bv && on < bn);
                bv = cc ? ov : bv;
                bn = cc ? on : bn;
            }
            lastD = bv; lastN = bn;
            if (lane == 0) { cand_d[obase + r] = bv; cand_n[obase + r] = bn; }
        }
    }
}

// Kernel A2: one wave per pair merges 36 candidates (one per lane),
// extracts the global top-9 and does the bbox L1 + GIoU epilogue.
__global__ __launch_bounds__(256) void topk_merge_kernel(
    const float* __restrict__ pred_boxes,  // (B,N,4)
    const float* __restrict__ gt_boxes,    // (B,G,4)
    const float* __restrict__ cand_d,
    const int*   __restrict__ cand_n,
    double* __restrict__ acc,
    int* __restrict__ sel)
{
    int wv   = threadIdx.x >> 6;
    int lane = threadIdx.x & 63;
    int pair = blockIdx.x * 4 + wv;        // 0..1023
    int b = pair >> 6;
    int g = pair & (GG - 1);

    const float4 gt = ((const float4*)gt_boxes)[b * GG + g];

    float vd = FLT_MAX; int vn = 0x7fffffff;
    if (lane < NSEG * KK) {
        vd = cand_d[pair * NSEG * KK + lane];
        vn = cand_n[pair * NSEG * KK + lane];
    }

    int myn = 0;
    for (int r = 0; r < KK; ++r) {
        float bv = vd; int bn = vn;
        for (int s = 1; s < 64; s <<= 1) {
            float ov = __shfl_xor(bv, s);
            int   on = __shfl_xor(bn, s);
            bool cc = (ov < bv) || (ov == bv && on < bn);
            bv = cc ? ov : bv;
            bn = cc ? on : bn;
        }
        if (vn == bn) vd = FLT_MAX;   // n unique across lanes
        if (lane == r) myn = bn;
        if (lane == 0) sel[pair * KK + r] = bn;
    }
    myn = myn < 0 ? 0 : (myn >= NN ? NN - 1 : myn);  // fault guard

    float l1 = 0.0f, gio = 0.0f;
    if (lane < KK) {
        float4 p = ((const float4*)pred_boxes)[b * NN + myn];
        l1 = fabsf(p.x - gt.x) + fabsf(p.y - gt.y) + fabsf(p.z - gt.z) + fabsf(p.w - gt.w);

        float ax1 = p.x - 0.5f * p.z, ay1 = p.y - 0.5f * p.w;
        float ax2 = p.x + 0.5f * p.z, ay2 = p.y + 0.5f * p.w;
        float bx1 = gt.x - 0.5f * gt.z, by1 = gt.y - 0.5f * gt.w;
        float bx2 = gt.x + 0.5f * gt.z, by2 = gt.y + 0.5f * gt.w;

        float area_a = (ax2 - ax1) * (ay2 - ay1);
        float area_b = (bx2 - bx1) * (by2 - by1);
        float ix1 = fmaxf(ax1, bx1), iy1 = fmaxf(ay1, by1);
        float ix2 = fminf(ax2, bx2), iy2 = fminf(ay2, by2);
        float iw = fmaxf(ix2 - ix1, 0.0f), ih = fmaxf(iy2 - iy1, 0.0f);
        float inter = iw * ih;
        float uni = area_a + area_b - inter;
        float iou = inter / uni;
        float ccx1 = fminf(ax1, bx1), ccy1 = fminf(ay1, by1);
        float ccx2 = fmaxf(ax2, bx2), ccy2 = fmaxf(ay2, by2);
        float cw = fmaxf(ccx2 - ccx1, 0.0f), ch = fmaxf(ccy2 - ccy1, 0.0f);
        float ac = cw * ch;
        float giou = iou - (ac - uni) / ac;
        gio = 1.0f - giou;
    }
    for (int o = 32; o > 0; o >>= 1) {
        l1 += __shfl_down(l1, o);
        gio += __shfl_down(gio, o);
    }
    if (lane == 0) {
        atomicAdd(&acc[1], (double)l1);
        atomicAdd(&acc[2], (double)gio);
    }
}

// Kernel B: main focal sum over all B*N*C logits (t=0 formula everywhere)
__global__ __launch_bounds__(256) void focal_main_kernel(
    const float* __restrict__ logits, double* __restrict__ acc, int nvec4)
{
    const float4* v = (const float4*)logits;
    float s0 = 0.f, s1 = 0.f, s2 = 0.f, s3 = 0.f;
    int stride = gridDim.x * blockDim.x;
    for (int i = blockIdx.x * blockDim.x + threadIdx.x; i < nvec4; i += stride) {
        float4 x = v[i];
        s0 += focal_t0(x.x);
        s1 += focal_t0(x.y);
        s2 += focal_t0(x.z);
        s3 += focal_t0(x.w);
    }
    double d = (double)((s0 + s1) + (s2 + s3));
#pragma unroll
    for (int o = 32; o > 0; o >>= 1) d += __shfl_down(d, o);
    __shared__ double wsum[4];
    if ((threadIdx.x & 63) == 0) wsum[threadIdx.x >> 6] = d;
    __syncthreads();
    if (threadIdx.x == 0) {
        atomicAdd(&acc[0], wsum[0] + wsum[1] + wsum[2] + wsum[3]);
    }
}

// Kernel C (v4): dedup + correction + FUSED finalize via device-atomic ticket.
#define EPB 144   // elements per block (576 / 4)
__global__ __launch_bounds__(256) void correction_kernel(
    const float* __restrict__ logits, const int* __restrict__ sel,
    const int* __restrict__ gt_labels, double* __restrict__ acc,
    int* __restrict__ ticket, float* __restrict__ out)
{
    int bq = blockIdx.x;           // 0..63
    int b  = bq >> 2;              // image
    int q  = bq & 3;               // quarter

    __shared__ int keys[GG * KK];
    for (int e = threadIdx.x; e < GG * KK; e += blockDim.x) {
        int g = e / KK;
        int n = sel[(b * GG + g) * KK + (e - g * KK)];
        keys[e] = n * CC + gt_labels[b * GG + g];
    }
    __syncthreads();

    bool active = (threadIdx.x < EPB);
    int e = q * EPB + (active ? threadIdx.x : 0);   // bounded index
    int k = keys[e];
    k = active ? k : -1;                            // -1 never matches

    // branch-free duplicate test, 8 pipelined LDS reads per group
    int dup = 0;
    for (int e2 = 0; e2 < GG * KK; e2 += 8) {
        int k0 = keys[e2 + 0];
        int k1 = keys[e2 + 1];
        int k2 = keys[e2 + 2];
        int k3 = keys[e2 + 3];
        int k4 = keys[e2 + 4];
        int k5 = keys[e2 + 5];
        int k6 = keys[e2 + 6];
        int k7 = keys[e2 + 7];
        int h = 0;
        h |= (int)(k0 == k) & (int)(e2 + 0 < e);
        h |= (int)(k1 == k) & (int)(e2 + 1 < e);
        h |= (int)(k2 == k) & (int)(e2 + 2 < e);
        h |= (int)(k3 == k) & (int)(e2 + 3 < e);
        h |= (int)(k4 == k) & (int)(e2 + 4 < e);
        h |= (int)(k5 == k) & (int)(e2 + 5 < e);
        h |= (int)(k6 == k) & (int)(e2 + 6 < e);
        h |= (int)(k7 == k) & (int)(e2 + 7 < e);
        dup |= h;
    }

    float corr = 0.0f;
    if (active && dup == 0) {
        corr = focal_corr(logits[(long long)b * NN * CC + k]);
    }

    double d = (double)corr;
#pragma unroll
    for (int o = 32; o > 0; o >>= 1) d += __shfl_down(d, o);
    __shared__ double wsum[4];
    if ((threadIdx.x & 63) == 0) wsum[threadIdx.x >> 6] = d;
    __syncthreads();
    __shared__ int amlast;
    if (threadIdx.x == 0) {
        atomicAdd(&acc[0], wsum[0] + wsum[1] + wsum[2] + wsum[3]);
        __threadfence();                       // my add visible before ticket
        int t = atomicAdd(ticket, 1);
        amlast = (t == (int)gridDim.x - 1) ? 1 : 0;
    }
    __syncthreads();
    if (threadIdx.x == 0 && amlast) {
        // all 64 blocks' acc[0] adds are ordered before this (ticket+fence);
        // acc[1], acc[2] were completed by earlier kernels (stream order).
        double a0 = atomicAdd(&acc[0], 0.0);
        double a1 = atomicAdd(&acc[1], 0.0);
        double a2 = atomicAdd(&acc[2], 0.0);
        out[0] = (float)(a0 / (double)((long long)BB * NN * CC));
        out[1] = (float)(a1 / (double)(BB * GG * KK * 4));
        out[2] = (float)(a2 / (double)(BB * GG * KK));
    }
}

extern "C" void kernel_launch(void* const* d_in, const int* in_sizes, int n_in,
                              void* d_out, int out_size, void* d_ws, size_t ws_size,
                              hipStream_t stream) {
    const float* pred_logits = (const float*)d_in[0];  // (B,N,C)
    const float* pred_boxes  = (const float*)d_in[1];  // (B,N,4)
    const float* locations   = (const float*)d_in[2];  // (N,2)
    const float* gt_boxes    = (const float*)d_in[3];  // (B,G,4)
    const int*   gt_labels   = (const int*)d_in[4];    // (B,G)
    float* out = (float*)d_out;

    // workspace layout: 64B header (acc[3] doubles + ticket int + pad)
    unsigned long long* hdr = (unsigned long long*)d_ws;
    double* acc    = (double*)d_ws;
    int*    ticket = (int*)((char*)d_ws + 24);
    int*    sel    = (int*)((char*)d_ws + 64);                    // 1024*9 ints
    float*  candd  = (float*)((char*)d_ws + 64 + 36864);          // 1024*4*9 floats
    int*    candn  = (int*)((char*)d_ws + 64 + 36864 + 147456);

    // A1: per-segment top-9 (1024 blocks x 4 waves); block 0 zeroes header
    topk_seg_kernel<<<BB * GG, 256, 0, stream>>>(locations, gt_boxes, candd, candn, hdr);

    // A2: merge 36 candidates/pair + bbox epilogue (256 blocks x 4 waves)
    topk_merge_kernel<<<BB * GG / 4, 256, 0, stream>>>(pred_boxes, gt_boxes, candd, candn, acc, sel);

    // B: focal main sum
    int nvec4 = (BB * NN * CC) / 4;
    focal_main_kernel<<<2048, 256, 0, stream>>>(pred_logits, acc, nvec4);

    // C: corrections + fused finalize (4 blocks per image, ticketed)
    correction_kernel<<<BB * 4, 256, 0, stream>>>(pred_logits, sel, gt_labels, acc, ticket, out);
}